// Round 1
// baseline (514.573 us; speedup 1.0000x reference)
//
#include <hip/hip_runtime.h>

// ---------------------------------------------------------------------------
// MHA forward: B=4, S=2048, D=1024, H=16, DH=64
//   q = query@Wq+bq ; k = key@Wk+bk ; v = value@Wv+bv   (per-head split)
//   ctx = softmax(q k^T / 8) v ; out = ctx@Wo + bo
// All GEMMs in bf16 MFMA (16x16x32), f32 accumulate. f32 in/out.
// ---------------------------------------------------------------------------

typedef __bf16 bf16x8 __attribute__((ext_vector_type(8)));
typedef float f32x4 __attribute__((ext_vector_type(4)));
typedef unsigned short u16x8 __attribute__((ext_vector_type(8)));

__device__ __forceinline__ unsigned short f2bf(float f) {
  union { float f; unsigned int u; } v; v.f = f;
  unsigned int u = v.u;
  unsigned int r = (u + 0x7fffu + ((u >> 16) & 1u)) >> 16;
  return (unsigned short)r;
}

// ---------------------------------------------------------------------------
// Weight transpose + f32->bf16:  W[k][n] (f32, 1024x1024) -> WT[n][k] (bf16)
// ---------------------------------------------------------------------------
__global__ __launch_bounds__(256) void wt_cvt(const float* __restrict__ w,
                                              unsigned short* __restrict__ wt) {
  __shared__ float t[32][33];
  const int n0 = blockIdx.x * 32, k0 = blockIdx.y * 32;
  const int x = threadIdx.x, y = threadIdx.y; // 32 x 8
#pragma unroll
  for (int i = 0; i < 32; i += 8) t[y + i][x] = w[(k0 + y + i) * 1024 + n0 + x];
  __syncthreads();
#pragma unroll
  for (int i = 0; i < 32; i += 8)
    wt[(n0 + y + i) * 1024 + (k0 + x)] = f2bf(t[x][y + i]);
}

// ---------------------------------------------------------------------------
// GEMM: C[M=8192][N=1024] = A[M][K=1024] * BT[N][K]^T + bias
// MODE 0: A=f32, out bf16 [B,H,S,DH]   (Q, K projections)
// MODE 1: A=f32, out bf16 [B,H,DH,S]   (V projection, transposed)
// MODE 2: A=bf16 (ctx),  out f32 [M][N] (final projection)
// 128x128 block tile, BK=64, 4 waves (2x2), 16x16x32 bf16 MFMA.
// LDS XOR-swizzle: phys = row*128 + (byte_in_row ^ ((row&7)<<4))
// ---------------------------------------------------------------------------
template <int MODE>
__global__ __launch_bounds__(256) void gemm_k(const void* __restrict__ Ap,
                                              const unsigned short* __restrict__ BT,
                                              const float* __restrict__ bias,
                                              void* __restrict__ outp) {
  __shared__ __align__(16) char smem[32768];
  char* As = smem;           // [128][64] bf16 = 16KB, swizzled
  char* Bs = smem + 16384;   // [128][64] bf16 = 16KB, swizzled
  const int tid = threadIdx.x;
  const int wid = tid >> 6, lane = tid & 63;
  const int wr = wid >> 1, wc = wid & 1;
  const int m0 = blockIdx.y * 128, n0 = blockIdx.x * 128;
  const int lr = lane & 15, lg = lane >> 4;

  f32x4 acc[4][4] = {};

  for (int k0 = 0; k0 < 1024; k0 += 64) {
    // ---- stage A and B tiles (reg path, swizzled writes) ----
#pragma unroll
    for (int it = 0; it < 4; ++it) {
      const int ci = tid + it * 256;     // 0..1023, 8-elem chunks
      const int row = ci >> 3, c = ci & 7;
      const int gk = k0 + c * 8;
      u16x8 av;
      if (MODE == 2) {
        av = *(const u16x8*)((const unsigned short*)Ap + (m0 + row) * 1024 + gk);
      } else {
        const float4 f0 = *(const float4*)((const float*)Ap + (m0 + row) * 1024 + gk);
        const float4 f1 = *(const float4*)((const float*)Ap + (m0 + row) * 1024 + gk + 4);
        av[0] = f2bf(f0.x); av[1] = f2bf(f0.y); av[2] = f2bf(f0.z); av[3] = f2bf(f0.w);
        av[4] = f2bf(f1.x); av[5] = f2bf(f1.y); av[6] = f2bf(f1.z); av[7] = f2bf(f1.w);
      }
      *(u16x8*)(As + row * 128 + ((c * 16) ^ ((row & 7) << 4))) = av;
      const u16x8 bv = *(const u16x8*)(BT + (n0 + row) * 1024 + gk);
      *(u16x8*)(Bs + row * 128 + ((c * 16) ^ ((row & 7) << 4))) = bv;
    }
    __syncthreads();

    // ---- MFMA inner loop ----
#pragma unroll
    for (int ks = 0; ks < 2; ++ks) {
      bf16x8 af[4], bfv[4];
#pragma unroll
      for (int i = 0; i < 4; ++i) {
        const int arow = wr * 64 + i * 16 + lr;
        af[i] = *(const bf16x8*)(As + arow * 128 +
                                 ((ks * 64 + lg * 16) ^ ((arow & 7) << 4)));
        const int brow = wc * 64 + i * 16 + lr;
        bfv[i] = *(const bf16x8*)(Bs + brow * 128 +
                                  ((ks * 64 + lg * 16) ^ ((brow & 7) << 4)));
      }
#pragma unroll
      for (int i = 0; i < 4; ++i)
#pragma unroll
        for (int j = 0; j < 4; ++j)
          acc[i][j] = __builtin_amdgcn_mfma_f32_16x16x32_bf16(af[i], bfv[j], acc[i][j], 0, 0, 0);
    }
    __syncthreads();
  }

  // ---- epilogue ----
#pragma unroll
  for (int i = 0; i < 4; ++i) {
#pragma unroll
    for (int j = 0; j < 4; ++j) {
      const int n = n0 + wc * 64 + j * 16 + lr;
      const float bb = bias[n];
#pragma unroll
      for (int r = 0; r < 4; ++r) {
        const int m = m0 + wr * 64 + i * 16 + lg * 4 + r;
        const float v = acc[i][j][r] + bb;
        if (MODE == 2) {
          ((float*)outp)[m * 1024 + n] = v;
        } else {
          const int b = m >> 11, s = m & 2047;
          const int h = n >> 6, dh = n & 63;
          if (MODE == 0)  // [B,H,S,DH]
            ((unsigned short*)outp)[(((b * 16 + h) * 2048 + s) << 6) + dh] = f2bf(v);
          else            // [B,H,DH,S]
            ((unsigned short*)outp)[(((b * 16 + h) * 64 + dh) << 11) + s] = f2bf(v);
        }
      }
    }
  }
}

// ---------------------------------------------------------------------------
// Flash attention: per block = one (b,h), 64 q-rows (16 per wave).
// Qp,Kp: [B*H][S][64] bf16 ; Vt: [B*H][64][S] bf16 ; ctx: [B][S][1024] bf16
// KV tiles of 64; K,V staged in swizzled LDS; per-wave P tile in LDS.
// ---------------------------------------------------------------------------
__global__ __launch_bounds__(256) void attn_k(const unsigned short* __restrict__ Qp,
                                              const unsigned short* __restrict__ Kp,
                                              const unsigned short* __restrict__ Vt,
                                              unsigned short* __restrict__ ctx) {
  __shared__ __align__(16) char smem[24576];
  char* Ks = smem;          // [64][64] bf16 swizzled (kv, dh)
  char* Vs = smem + 8192;   // [64][64] bf16 swizzled (dh, kv)
  char* Ps = smem + 16384;  // 4 waves x [16][64] bf16 swizzled (q, kv)
  const int tid = threadIdx.x, wid = tid >> 6, lane = tid & 63;
  const int lr = lane & 15, lg = lane >> 4;
  const int bh = blockIdx.y;                 // b*16 + h
  const int q0 = blockIdx.x * 64 + wid * 16; // this wave's q rows
  const int S = 2048;

  // Q fragments in registers (A-operand: row=lr, k=lg*8.. within 64)
  bf16x8 aq[2];
#pragma unroll
  for (int ks = 0; ks < 2; ++ks)
    aq[ks] = *(const bf16x8*)(Qp + (bh * S + q0 + lr) * 64 + ks * 32 + lg * 8);

  float m_run[4], l_run[4];
  f32x4 acc_o[4] = {};
#pragma unroll
  for (int j = 0; j < 4; ++j) { m_run[j] = -1e30f; l_run[j] = 0.f; }

  for (int kv0 = 0; kv0 < S; kv0 += 64) {
    // ---- stage K [64 kv][64 dh] and V^T [64 dh][64 kv] ----
#pragma unroll
    for (int it = 0; it < 2; ++it) {
      const int ci = tid + it * 256;   // 0..511
      const int r = ci >> 3, c = ci & 7;
      const u16x8 kv = *(const u16x8*)(Kp + (bh * S + kv0 + r) * 64 + c * 8);
      *(u16x8*)(Ks + r * 128 + ((c * 16) ^ ((r & 7) << 4))) = kv;
      const u16x8 vv = *(const u16x8*)(Vt + (bh * 64 + r) * S + kv0 + c * 8);
      *(u16x8*)(Vs + r * 128 + ((c * 16) ^ ((r & 7) << 4))) = vv;
    }
    __syncthreads();

    // ---- scores = Q K^T (per wave: 16 q x 64 kv) ----
    f32x4 sc[4] = {};
#pragma unroll
    for (int cb = 0; cb < 4; ++cb) {
#pragma unroll
      for (int ks = 0; ks < 2; ++ks) {
        const int krow = cb * 16 + lr;
        const bf16x8 bk = *(const bf16x8*)(Ks + krow * 128 +
                                           ((ks * 64 + lg * 16) ^ ((krow & 7) << 4)));
        sc[cb] = __builtin_amdgcn_mfma_f32_16x16x32_bf16(aq[ks], bk, sc[cb], 0, 0, 0);
      }
    }

    // ---- online softmax (rows lg*4+j; cols spread over 16 lanes x 4 cb) ----
#pragma unroll
    for (int j = 0; j < 4; ++j) {
      float mx = fmaxf(fmaxf(sc[0][j], sc[1][j]), fmaxf(sc[2][j], sc[3][j]));
      mx *= 0.125f;
#pragma unroll
      for (int off = 1; off < 16; off <<= 1)
        mx = fmaxf(mx, __shfl_xor(mx, off, 64));
      const float mnew = fmaxf(m_run[j], mx);
      const float corr = __expf(m_run[j] - mnew);
      m_run[j] = mnew;
      float rs = 0.f;
      unsigned short pb[4];
#pragma unroll
      for (int cb = 0; cb < 4; ++cb) {
        const float p = __expf(sc[cb][j] * 0.125f - mnew);
        rs += p;
        pb[cb] = f2bf(p);
      }
#pragma unroll
      for (int off = 1; off < 16; off <<= 1)
        rs += __shfl_xor(rs, off, 64);
      l_run[j] = l_run[j] * corr + rs;
      const int prow = lg * 4 + j;
#pragma unroll
      for (int cb = 0; cb < 4; ++cb)
        *(unsigned short*)(Ps + wid * 2048 + prow * 128 +
                           (((cb * 16 + lr) * 2) ^ ((prow & 7) << 4))) = pb[cb];
#pragma unroll
      for (int dhb = 0; dhb < 4; ++dhb) acc_o[dhb][j] *= corr;
    }

    // ---- PV: out += P[16 x 64] * V[64 x 64] ----
    bf16x8 pa[2];
#pragma unroll
    for (int ks = 0; ks < 2; ++ks)
      pa[ks] = *(const bf16x8*)(Ps + wid * 2048 + lr * 128 +
                                ((ks * 64 + lg * 16) ^ ((lr & 7) << 4)));
#pragma unroll
    for (int dhb = 0; dhb < 4; ++dhb) {
#pragma unroll
      for (int ks = 0; ks < 2; ++ks) {
        const int vrow = dhb * 16 + lr;
        const bf16x8 bv = *(const bf16x8*)(Vs + vrow * 128 +
                                           ((ks * 64 + lg * 16) ^ ((vrow & 7) << 4)));
        acc_o[dhb] = __builtin_amdgcn_mfma_f32_16x16x32_bf16(pa[ks], bv, acc_o[dhb], 0, 0, 0);
      }
    }
    __syncthreads();
  }

  // ---- epilogue: ctx[b][s][h*64+dh] = acc / l ----
  const int b = bh >> 4, h = bh & 15;
#pragma unroll
  for (int dhb = 0; dhb < 4; ++dhb) {
#pragma unroll
    for (int j = 0; j < 4; ++j) {
      const float v = acc_o[dhb][j] / l_run[j];
      const int srow = q0 + lg * 4 + j;
      const int d = h * 64 + dhb * 16 + lr;
      ctx[(b * 2048 + srow) * 1024 + d] = f2bf(v);
    }
  }
}

// ---------------------------------------------------------------------------
extern "C" void kernel_launch(void* const* d_in, const int* in_sizes, int n_in,
                              void* d_out, int out_size, void* d_ws, size_t ws_size,
                              hipStream_t stream) {
  const float* query = (const float*)d_in[0];
  const float* key   = (const float*)d_in[1];
  const float* value = (const float*)d_in[2];
  const float* Wq = (const float*)d_in[3];
  const float* bq = (const float*)d_in[4];
  const float* Wk = (const float*)d_in[5];
  const float* bk = (const float*)d_in[6];
  const float* Wv = (const float*)d_in[7];
  const float* bv = (const float*)d_in[8];
  const float* Wo = (const float*)d_in[9];
  const float* bo = (const float*)d_in[10];

  char* ws = (char*)d_ws;
  unsigned short* WqT = (unsigned short*)(ws + 0 * 2097152);
  unsigned short* WkT = (unsigned short*)(ws + 1 * 2097152);
  unsigned short* WvT = (unsigned short*)(ws + 2 * 2097152);
  unsigned short* WoT = (unsigned short*)(ws + 3 * 2097152);
  unsigned short* Qp  = (unsigned short*)(ws + 8388608);
  unsigned short* Kp  = (unsigned short*)(ws + 25165824);
  unsigned short* Vt  = (unsigned short*)(ws + 41943040);
  unsigned short* ctx = (unsigned short*)(ws + 58720256);

  const dim3 tb(32, 8);
  wt_cvt<<<dim3(32, 32), tb, 0, stream>>>(Wq, WqT);
  wt_cvt<<<dim3(32, 32), tb, 0, stream>>>(Wk, WkT);
  wt_cvt<<<dim3(32, 32), tb, 0, stream>>>(Wv, WvT);
  wt_cvt<<<dim3(32, 32), tb, 0, stream>>>(Wo, WoT);

  const dim3 gg(8, 64);  // N/128 x M/128
  gemm_k<0><<<gg, 256, 0, stream>>>(query, WqT, bq, Qp);
  gemm_k<0><<<gg, 256, 0, stream>>>(key,   WkT, bk, Kp);
  gemm_k<1><<<gg, 256, 0, stream>>>(value, WvT, bv, Vt);

  attn_k<<<dim3(32, 64), 256, 0, stream>>>(Qp, Kp, Vt, ctx);

  gemm_k<2><<<gg, 256, 0, stream>>>(ctx, WoT, bo, (float*)d_out);
}

// Round 8
// 398.312 us; speedup vs baseline: 1.2919x; 1.2919x over previous
//
#include <hip/hip_runtime.h>

// ---------------------------------------------------------------------------
// MHA forward: B=4, S=2048, D=1024, H=16, DH=64
// bf16 MFMA (16x16x32) everywhere, f32 accumulate.
// GEMMs: m97 structure (global_load_lds w=16, pre-swizzled src, linear LDS).
// Attention: swapped QK^T (lane-local softmax), dbuf K/V via global_load_lds.
// ---------------------------------------------------------------------------

typedef __bf16 bf16x8 __attribute__((ext_vector_type(8)));
typedef __bf16 bf16x4 __attribute__((ext_vector_type(4)));
typedef float f32x4 __attribute__((ext_vector_type(4)));

#define GLAS __attribute__((address_space(1)))
#define LDSAS __attribute__((address_space(3)))

__device__ __forceinline__ void gl16(const void* g, void* l) {
  __builtin_amdgcn_global_load_lds((GLAS void*)const_cast<void*>(g),
                                   (LDSAS void*)l, 16, 0, 0);
}

// ---------------------------------------------------------------------------
// Weight transpose + f32->bf16 (+scale): W[k][n] -> WT[n][k]
// ---------------------------------------------------------------------------
__global__ __launch_bounds__(256) void wt_cvt(const float* __restrict__ w,
                                              __bf16* __restrict__ wt, float scl) {
  __shared__ float t[32][33];
  const int n0 = blockIdx.x * 32, k0 = blockIdx.y * 32;
  const int x = threadIdx.x, y = threadIdx.y; // 32 x 8
#pragma unroll
  for (int i = 0; i < 32; i += 8) t[y + i][x] = w[(k0 + y + i) * 1024 + n0 + x];
  __syncthreads();
#pragma unroll
  for (int i = 0; i < 32; i += 8)
    wt[(n0 + y + i) * 1024 + (k0 + x)] = (__bf16)(t[x][y + i] * scl);
}

// ---------------------------------------------------------------------------
// Activation f32 -> bf16 (vectorized x8)
// ---------------------------------------------------------------------------
__global__ __launch_bounds__(256) void cvt_k(const float* __restrict__ in,
                                             __bf16* __restrict__ out) {
  const int i = (blockIdx.x * 256 + threadIdx.x) * 8;
  const float4 f0 = *(const float4*)(in + i);
  const float4 f1 = *(const float4*)(in + i + 4);
  bf16x8 o;
  o[0] = (__bf16)f0.x; o[1] = (__bf16)f0.y; o[2] = (__bf16)f0.z; o[3] = (__bf16)f0.w;
  o[4] = (__bf16)f1.x; o[5] = (__bf16)f1.y; o[6] = (__bf16)f1.z; o[7] = (__bf16)f1.w;
  *(bf16x8*)(out + i) = o;
}

// ---------------------------------------------------------------------------
// GEMM: C[M=8192][N=1024] = A[M][1024] * BT[N][1024]^T + bias*bsc
// A bf16 (pre-converted). 128x128 tile, BK=64, 4 waves (2x2).
// Staging via global_load_lds(16B), pre-swizzled source -> XOR layout in LDS;
// frag reads apply the same XOR -> ~conflict-free ds_read_b128.
// MODE 0: out bf16 [B,H,S,DH] ; MODE 1: out bf16 [B,H,DH,S] ; MODE 2: out f32
// ---------------------------------------------------------------------------
template <int MODE>
__global__ __launch_bounds__(256) void gemm_k(const __bf16* __restrict__ A,
                                              const __bf16* __restrict__ BT,
                                              const float* __restrict__ bias, float bsc,
                                              void* __restrict__ outp) {
  __shared__ __align__(16) char smem[32768]; // As 16KB | Bs 16KB, [128][64] bf16
  const int tid = threadIdx.x, wid = tid >> 6, lane = tid & 63;
  const int wr = wid >> 1, wc = wid & 1;
  const int m0 = blockIdx.y * 128, n0 = blockIdx.x * 128;
  const int lr = lane & 15, lg = lane >> 4;

  const int srow = lane >> 3;          // == row&7 for every chunk
  const int scl8 = (lane & 7) ^ srow;  // pre-swizzled 16B col-chunk
  const __bf16* Ab = A + (m0 + wid * 32 + srow) * 1024 + scl8 * 8;
  const __bf16* Bb = BT + (n0 + wid * 32 + srow) * 1024 + scl8 * 8;
  char* AsW = smem + wid * 4096;
  char* BsW = smem + 16384 + wid * 4096;

  f32x4 acc[4][4] = {};

  for (int k0 = 0; k0 < 1024; k0 += 64) {
#pragma unroll
    for (int i = 0; i < 4; ++i) {
      gl16(Ab + i * 8192 + k0, AsW + i * 1024);
      gl16(Bb + i * 8192 + k0, BsW + i * 1024);
    }
    __syncthreads();
#pragma unroll
    for (int ks = 0; ks < 2; ++ks) {
      bf16x8 af[4], bfv[4];
      const int co = (ks * 64 + lg * 16) ^ ((lr & 7) << 4);
#pragma unroll
      for (int i = 0; i < 4; ++i) {
        af[i]  = *(const bf16x8*)(smem + (wr * 64 + i * 16 + lr) * 128 + co);
        bfv[i] = *(const bf16x8*)(smem + 16384 + (wc * 64 + i * 16 + lr) * 128 + co);
      }
#pragma unroll
      for (int i = 0; i < 4; ++i)
#pragma unroll
        for (int j = 0; j < 4; ++j)
          acc[i][j] = __builtin_amdgcn_mfma_f32_16x16x32_bf16(af[i], bfv[j], acc[i][j], 0, 0, 0);
    }
    __syncthreads();
  }

#pragma unroll
  for (int i = 0; i < 4; ++i)
#pragma unroll
    for (int j = 0; j < 4; ++j) {
      const int n = n0 + wc * 64 + j * 16 + lr;
      const float bb = bias[n] * bsc;
#pragma unroll
      for (int r = 0; r < 4; ++r) {
        const int m = m0 + wr * 64 + i * 16 + lg * 4 + r;
        const float v = acc[i][j][r] + bb;
        if (MODE == 2) {
          ((float*)outp)[m * 1024 + n] = v;
        } else {
          const int b = m >> 11, s = m & 2047;
          const int h = n >> 6, dh = n & 63;
          if (MODE == 0)
            ((__bf16*)outp)[(((b * 16 + h) * 2048 + s) << 6) + dh] = (__bf16)v;
          else
            ((__bf16*)outp)[(((b * 16 + h) * 64 + dh) << 11) + s] = (__bf16)v;
        }
      }
    }
}

// ---------------------------------------------------------------------------
// Flash attention. Qp,Kp: [B*H][S][64] bf16 ; Vt: [B*H][64][S] bf16
// ctx: [B][S][1024] bf16. Block = (b,h) x 64 q-rows; wave owns 16 q-rows.
// Swapped QK^T: sc = mfma(K, Q) = S^T -> lane owns q = lane&15, 16 kv values.
// K/V double-buffered via global_load_lds, pre-swizzled sources (rule 21).
// Wq pre-scaled by 0.125*log2(e) -> softmax in exp2 domain (1-inst v_exp).
// ---------------------------------------------------------------------------
__global__ __launch_bounds__(256) void attn_k(const __bf16* __restrict__ Qp,
                                              const __bf16* __restrict__ Kp,
                                              const __bf16* __restrict__ Vt,
                                              __bf16* __restrict__ ctx) {
  __shared__ __align__(16) char smem[40960];
  // Ks: 2x8KB @0 ; Vs: 2x8KB @16384 ; Ps: 4 waves x 2KB @32768
  const int tid = threadIdx.x, wid = tid >> 6, lane = tid & 63;
  const int lr = lane & 15, lg = lane >> 4;
  const int bh = blockIdx.y;
  const int q0 = blockIdx.x * 64 + wid * 16;
  const int S = 2048;

  const int srow = lane >> 3;
  const int scl8 = (lane & 7) ^ srow;
  const __bf16* Kbase = Kp + (bh * S + srow) * 64 + scl8 * 8;
  const __bf16* Vbase = Vt + (bh * 64 + srow) * S + scl8 * 8;
  char* Ps = smem + 32768 + wid * 2048;

  bf16x8 aq[2];
#pragma unroll
  for (int ks = 0; ks < 2; ++ks)
    aq[ks] = *(const bf16x8*)(Qp + (bh * S + q0 + lr) * 64 + ks * 32 + lg * 8);

  float m_run = -1e30f, l_run = 0.f;
  f32x4 acc_o[4] = {};

  // prologue: stage tile 0 -> buf 0 (chunks wid*2, wid*2+1)
#pragma unroll
  for (int i = 0; i < 2; ++i) {
    const int ch = wid * 2 + i;
    gl16(Kbase + ch * 512, smem + ch * 1024);
    gl16(Vbase + ch * 16384, smem + 16384 + ch * 1024);
  }

  int cur = 0;
  for (int t = 0; t < 32; ++t) {
    __syncthreads(); // drain vmcnt -> buf[cur] ready; all prev reads done
    if (t + 1 < 32) {
      const int kv1 = (t + 1) * 64;
      char* Kd = smem + (cur ^ 1) * 8192;
      char* Vd = smem + 16384 + (cur ^ 1) * 8192;
#pragma unroll
      for (int i = 0; i < 2; ++i) {
        const int ch = wid * 2 + i;
        gl16(Kbase + kv1 * 64 + ch * 512, Kd + ch * 1024);
        gl16(Vbase + kv1 + ch * 16384, Vd + ch * 1024);
      }
    }
    const char* Ks = smem + cur * 8192;
    const char* Vs = smem + 16384 + cur * 8192;

    // ---- QK^T (swapped): sc[cb][r] = S^T[kv=cb*16+lg*4+r][q=lr] ----
    f32x4 sc[4] = {};
    __builtin_amdgcn_s_setprio(1);
#pragma unroll
    for (int cb = 0; cb < 4; ++cb) {
#pragma unroll
      for (int ks = 0; ks < 2; ++ks) {
        const int krow = cb * 16 + lr;
        const bf16x8 kf = *(const bf16x8*)(Ks + krow * 128 +
                                           ((ks * 64 + lg * 16) ^ ((krow & 7) << 4)));
        sc[cb] = __builtin_amdgcn_mfma_f32_16x16x32_bf16(kf, aq[ks], sc[cb], 0, 0, 0);
      }
    }
    __builtin_amdgcn_s_setprio(0);

    // ---- online softmax: lane-local row + 2-shfl cross-group reduce ----
    float mx = sc[0][0];
#pragma unroll
    for (int cb = 0; cb < 4; ++cb)
#pragma unroll
      for (int r = 0; r < 4; ++r) mx = fmaxf(mx, sc[cb][r]);
    mx = fmaxf(mx, __shfl_xor(mx, 16, 64));
    mx = fmaxf(mx, __shfl_xor(mx, 32, 64));
    const float mnew = fmaxf(m_run, mx);
    const float corr = __builtin_amdgcn_exp2f(m_run - mnew);
    m_run = mnew;
    float rs = 0.f;
#pragma unroll
    for (int cb = 0; cb < 4; ++cb) {
      bf16x4 pk;
#pragma unroll
      for (int r = 0; r < 4; ++r) {
        const float p = __builtin_amdgcn_exp2f(sc[cb][r] - mnew);
        rs += p;
        pk[r] = (__bf16)p;
      }
      // P[q=lr][kv=cb*16+lg*4 .. +3], packed b64, swizzled
      *(bf16x4*)(Ps + lr * 128 + ((cb * 32 + lg * 8) ^ ((lr & 7) << 4))) = pk;
    }
    rs += __shfl_xor(rs, 16, 64);
    rs += __shfl_xor(rs, 32, 64);
    l_run = l_run * corr + rs;
    float corrv[4];
#pragma unroll
    for (int r = 0; r < 4; ++r) corrv[r] = __shfl(corr, lg * 4 + r, 64);
#pragma unroll
    for (int dhb = 0; dhb < 4; ++dhb)
#pragma unroll
      for (int r = 0; r < 4; ++r) acc_o[dhb][r] *= corrv[r];

    // ---- PV: acc_o += P[16x64] * V[64x64] ----
    bf16x8 pa[2];
#pragma unroll
    for (int ks = 0; ks < 2; ++ks)
      pa[ks] = *(const bf16x8*)(Ps + lr * 128 + ((ks * 64 + lg * 16) ^ ((lr & 7) << 4)));
    __builtin_amdgcn_s_setprio(1);
#pragma unroll
    for (int dhb = 0; dhb < 4; ++dhb) {
#pragma unroll
      for (int ks = 0; ks < 2; ++ks) {
        const int vrow = dhb * 16 + lr;
        const bf16x8 vf = *(const bf16x8*)(Vs + vrow * 128 +
                                           ((ks * 64 + lg * 16) ^ ((vrow & 7) << 4)));
        acc_o[dhb] = __builtin_amdgcn_mfma_f32_16x16x32_bf16(pa[ks], vf, acc_o[dhb], 0, 0, 0);
      }
    }
    __builtin_amdgcn_s_setprio(0);
    cur ^= 1;
  }

  // ---- epilogue: ctx[b][s][h*64+dh] = acc / l ----
  const int b = bh >> 4, h = bh & 15;
  float linv[4];
#pragma unroll
  for (int r = 0; r < 4; ++r) linv[r] = 1.f / __shfl(l_run, lg * 4 + r, 64);
#pragma unroll
  for (int dhb = 0; dhb < 4; ++dhb)
#pragma unroll
    for (int r = 0; r < 4; ++r) {
      const int sr = q0 + lg * 4 + r;
      const int d = h * 64 + dhb * 16 + lr;
      ctx[(b * 2048 + sr) * 1024 + d] = (__bf16)(acc_o[dhb][r] * linv[r]);
    }
}

// ---------------------------------------------------------------------------
extern "C" void kernel_launch(void* const* d_in, const int* in_sizes, int n_in,
                              void* d_out, int out_size, void* d_ws, size_t ws_size,
                              hipStream_t stream) {
  const float* query = (const float*)d_in[0];
  const float* key   = (const float*)d_in[1];
  const float* value = (const float*)d_in[2];
  const float* Wq = (const float*)d_in[3];
  const float* bq = (const float*)d_in[4];
  const float* Wk = (const float*)d_in[5];
  const float* bk = (const float*)d_in[6];
  const float* Wv = (const float*)d_in[7];
  const float* bv = (const float*)d_in[8];
  const float* Wo = (const float*)d_in[9];
  const float* bo = (const float*)d_in[10];

  char* ws = (char*)d_ws;
  __bf16* WqT = (__bf16*)(ws + 0 * 2097152);
  __bf16* WkT = (__bf16*)(ws + 1 * 2097152);
  __bf16* WvT = (__bf16*)(ws + 2 * 2097152);
  __bf16* WoT = (__bf16*)(ws + 3 * 2097152);
  __bf16* Abf = (__bf16*)(ws + 8388608);   // 16.8MB staging, reused as ctx
  __bf16* Qp  = (__bf16*)(ws + 25165824);
  __bf16* Kp  = (__bf16*)(ws + 41943040);
  __bf16* Vt  = (__bf16*)(ws + 58720256);
  __bf16* ctx = Abf;

  const float SCL = 0.125f * 1.44269504088896340736f; // fold /8 and log2(e) into Q

  const dim3 tb(32, 8);
  wt_cvt<<<dim3(32, 32), tb, 0, stream>>>(Wq, WqT, SCL);
  wt_cvt<<<dim3(32, 32), tb, 0, stream>>>(Wk, WkT, 1.f);
  wt_cvt<<<dim3(32, 32), tb, 0, stream>>>(Wv, WvT, 1.f);
  wt_cvt<<<dim3(32, 32), tb, 0, stream>>>(Wo, WoT, 1.f);

  const dim3 gg(8, 64);  // N/128 x M/128
  cvt_k<<<4096, 256, 0, stream>>>(query, Abf);
  gemm_k<0><<<gg, 256, 0, stream>>>(Abf, WqT, bq, SCL, Qp);
  cvt_k<<<4096, 256, 0, stream>>>(key, Abf);
  gemm_k<0><<<gg, 256, 0, stream>>>(Abf, WkT, bk, 1.f, Kp);
  cvt_k<<<4096, 256, 0, stream>>>(value, Abf);
  gemm_k<1><<<gg, 256, 0, stream>>>(Abf, WvT, bv, 1.f, Vt);

  attn_k<<<dim3(32, 64), 256, 0, stream>>>(Qp, Kp, Vt, ctx);

  gemm_k<2><<<gg, 256, 0, stream>>>(ctx, WoT, bo, 1.f, (float*)d_out);
}